// Round 15
// baseline (139.219 us; speedup 1.0000x reference)
//
#include <hip/hip_runtime.h>
#include <hip/hip_bf16.h>

typedef __attribute__((ext_vector_type(8))) short bf16x8_t;
typedef __attribute__((ext_vector_type(4))) float f32x4_t;

#define B_   4
#define C_   512
#define N_   4096
#define NQK_ 128   // Q(64) | K(64) channel-concat width
#define NT_  128   // N_/32 j-tiles
#define NP_  64    // 2-tile barrier periods
#define LOG2E_ 1.44269504088896340736f
#define THR2_  11.5415603f   // 8 * log2e — defer-max threshold in log2 domain

typedef unsigned short ushort_t;

__device__ __forceinline__ ushort_t f2bf(float f) {
    union { float f; unsigned int u; } un; un.f = f;
    unsigned int r = un.u + 0x7FFF + ((un.u >> 16) & 1); // RNE
    return (ushort_t)(r >> 16);
}

__device__ __forceinline__ bf16x8_t load8(const ushort_t* p) {
    return *reinterpret_cast<const bf16x8_t*>(p);
}

// lane[i] <-> lane[i^32] max via v_permlane32_swap_b32 (VALU pipe) replacing
// the ds-pipe __shfl_xor hop. Value-semantics builtin (round 10's raw-asm
// self-swap aliasing trap does not apply). max(r0,r1) is correct under
// EITHER swap orientation: each output lane holds self or partner.
__device__ __forceinline__ float xmax32(float x) {
    unsigned u = __float_as_uint(x);
    auto r = __builtin_amdgcn_permlane32_swap(u, u, false, false);
    return fmaxf(__uint_as_float(r[0]), __uint_as_float(r[1]));
}

// lane[i] <-> lane[i^16] max via v_permlane16_swap_b32 — same argument.
// With both, the whole pmax reduce is VALU-only (zero lgkm round-trips).
__device__ __forceinline__ float xmax16(float x) {
    unsigned u = __float_as_uint(x);
    auto r = __builtin_amdgcn_permlane16_swap(u, u, false, false);
    return fmaxf(__uint_as_float(r[0]), __uint_as_float(r[1]));
}

// async global->LDS, 16B per lane; dest is wave-uniform base (+ lane*16 in HW)
#define GLL16(g, l) __builtin_amdgcn_global_load_lds( \
    (const __attribute__((address_space(1))) unsigned int*)(g), \
    (__attribute__((address_space(3))) unsigned int*)(l), 16, 0, 0)

// ------------------------------------------- transpose+cast x -> Xt[b][n][c]
// z==4: weight/bias cast (folded-in former cast_w kernel)
__global__ __launch_bounds__(256) void transpose_cast_x(
        const float* __restrict__ x, ushort_t* __restrict__ Xt,
        const float* __restrict__ w1, const float* __restrict__ b1,
        const float* __restrict__ w2, const float* __restrict__ b2,
        const float* __restrict__ w3, const float* __restrict__ b3,
        ushort_t* __restrict__ Wb, float* __restrict__ bias_all) {
    if (blockIdx.z == 4) {
        int bid = blockIdx.y * 64 + blockIdx.x;          // 0..511
        int t0 = bid * 256 + threadIdx.x;                // 0..131071
        for (int idx = t0; idx < 640 * 512 + 640; idx += 131072) {
            if (idx < 64 * 512) {
                Wb[idx] = f2bf(w1[idx]);
            } else if (idx < 128 * 512) {
                Wb[idx] = f2bf(w2[idx - 64 * 512]);
            } else if (idx < 640 * 512) {
                Wb[idx] = f2bf(w3[idx - 128 * 512]);
            } else {
                int i = idx - 640 * 512;
                bias_all[i] = (i < 64) ? b1[i] : (i < 128 ? b2[i - 64] : b3[i - 128]);
            }
        }
        return;
    }
    int b = blockIdx.z, c0 = blockIdx.y * 64, n0 = blockIdx.x * 64;
    int tid = threadIdx.x;
    __shared__ float t[64][65];
    const float* xb = x + ((size_t)b * C_ + c0) * N_ + n0;
    #pragma unroll
    for (int it = 0; it < 4; ++it) {
        int cl = it * 16 + (tid >> 4), nq = (tid & 15) * 4;
        const float4 v = *reinterpret_cast<const float4*>(xb + (size_t)cl * N_ + nq);
        t[cl][nq + 0] = v.x; t[cl][nq + 1] = v.y;
        t[cl][nq + 2] = v.z; t[cl][nq + 3] = v.w;
    }
    __syncthreads();
    #pragma unroll
    for (int it = 0; it < 4; ++it) {
        int nl = it * 16 + (tid >> 4), cq = (tid & 15) * 4;
        ushort4 o;
        o.x = f2bf(t[cq + 0][nl]); o.y = f2bf(t[cq + 1][nl]);
        o.z = f2bf(t[cq + 2][nl]); o.w = f2bf(t[cq + 3][nl]);
        *reinterpret_cast<ushort4*>(&Xt[((size_t)b * N_ + n0 + nl) * C_ + c0 + cq]) = o;
    }
}

// ---------------------------------------------------- fused QK + V GEMMs
// Uniform 64x128 output tiles, 1280 equal blocks (exactly 5/CU). 24KB LDS ->
// 2 blocks/CU co-resident. m97 staging recipe, vmcnt(3) cadence.
// Round 31: Q columns (wc==0, cols 0-63) are scaled by log2e at the
// epilogue, putting QK^T in the log2 domain — attn's softmax then uses bare
// v_exp_f32 (exp2f) with no per-element mul. K/V outputs unchanged.
__global__ __launch_bounds__(256) void gemm_qkv_kernel(
        const ushort_t* __restrict__ Xt, const ushort_t* __restrict__ Wb,
        const float* __restrict__ bias, ushort_t* __restrict__ QK,
        ushort_t* __restrict__ V) {
    __shared__ ushort_t Al[2][2048];   // 64 rows x 32 k, linear
    __shared__ ushort_t Bl[2][4096];   // 128 rows x 32 k, linear
    int bid = blockIdx.x;
    int tid = threadIdx.x;
    int l = tid & 63, w = tid >> 6;
    int wr = w >> 1, wc = w & 1;       // 2 row-strips(32) x 2 col-strips(64)
    int lr = l & 15, lg = l >> 4;

    int b, n0, d0 = 0;
    bool isQK = (bid < 256);
    const ushort_t* asrc;
    const ushort_t* bsrc;
    if (isQK) {
        b = bid >> 6; n0 = (bid & 63) * 64;
        asrc = Xt + ((size_t)b * N_ + n0) * 512;   // A rows = 64 n-rows
        bsrc = Wb;                                  // B rows = 128 qk cols
    } else {
        int v = bid - 256;
        b = v >> 8; d0 = ((v >> 5) & 7) * 64; n0 = (v & 31) * 128;
        asrc = Wb + (size_t)(128 + d0) * 512;       // A rows = 64 d-rows of Wv
        bsrc = Xt + ((size_t)b * N_ + n0) * 512;    // B rows = 128 n-rows
    }
    const ushort_t* ast = asrc + (size_t)(l >> 2) * 512 + (l & 3) * 8;
    const ushort_t* bst = bsrc + (size_t)(l >> 2) * 512 + (l & 3) * 8;

#define STAGEK(BUF, K0)                                                          \
    {                                                                            \
        GLL16(ast + (size_t)(w * 16) * 512 + (K0),      &Al[BUF][w * 512]);      \
        GLL16(bst + (size_t)(w * 32) * 512 + (K0),      &Bl[BUF][w * 1024]);     \
        GLL16(bst + (size_t)(w * 32 + 16) * 512 + (K0), &Bl[BUF][w * 1024 + 512]); \
    }

    f32x4_t acc[2][4] = {};
    STAGEK(0, 0)
    for (int i = 0; i < 16; ++i) {
        int cur = i & 1;
        if (i < 15) {
            STAGEK(cur ^ 1, (i + 1) * 32)
            asm volatile("s_waitcnt vmcnt(3)" ::: "memory");  // cur's 3 landed
        } else {
            asm volatile("s_waitcnt vmcnt(0)" ::: "memory");
        }
        asm volatile("" ::: "memory");
        __builtin_amdgcn_s_barrier();
        asm volatile("" ::: "memory");
        bf16x8_t a[2], b8[4];
        #pragma unroll
        for (int f = 0; f < 2; ++f)
            a[f]  = load8(&Al[cur][(wr * 32 + f * 16 + lr) * 32 + lg * 8]);
        #pragma unroll
        for (int f = 0; f < 4; ++f)
            b8[f] = load8(&Bl[cur][(wc * 64 + f * 16 + lr) * 32 + lg * 8]);
        #pragma unroll
        for (int fi = 0; fi < 2; ++fi)
            #pragma unroll
            for (int fj = 0; fj < 4; ++fj)
                acc[fi][fj] = __builtin_amdgcn_mfma_f32_16x16x32_bf16(
                    a[fi], b8[fj], acc[fi][fj], 0, 0, 0);
        asm volatile("" ::: "memory");
        __builtin_amdgcn_s_barrier();   // all reads of cur done before restage
        asm volatile("" ::: "memory");
    }
#undef STAGEK

    if (isQK) {
        // wc==0 covers Q columns (0-63): fold log2e into Q so QK^T lands in
        // the log2 domain (wave-uniform branch).
        float sc = (wc == 0) ? LOG2E_ : 1.0f;
        #pragma unroll
        for (int fi = 0; fi < 2; ++fi)
            #pragma unroll
            for (int fj = 0; fj < 4; ++fj)
                #pragma unroll
                for (int r = 0; r < 4; ++r) {
                    int n = n0 + wr * 32 + fi * 16 + lg * 4 + r;
                    int col = wc * 64 + fj * 16 + lr;
                    QK[((size_t)b * N_ + n) * NQK_ + col] =
                        f2bf((acc[fi][fj][r] + bias[col]) * sc);
                }
    } else {
        #pragma unroll
        for (int fi = 0; fi < 2; ++fi)
            #pragma unroll
            for (int fj = 0; fj < 4; ++fj)
                #pragma unroll
                for (int r = 0; r < 4; ++r) {
                    int d = d0 + wr * 32 + fi * 16 + lg * 4 + r;
                    int n = n0 + wc * 64 + fj * 16 + lr;
                    V[((size_t)b * C_ + d) * N_ + n] = f2bf(acc[fi][fj][r] + bias[128 + d]);
                }
    }
}

// ---------------------------------------------------- fused flash attention
// grid 256 x 768thr (12 waves). Round 31 = round 14 (136.6us, verified) with
// ONE isolated change: softmax in the log2 domain. Q was pre-scaled by log2e
// in gemm_qkv, so every __expf (v_mul + v_exp) becomes exp2f (bare
// v_exp_f32) — 16 muls/period off the S critical chain. Defer threshold
// 8.0 -> 8*log2e (P still bounded by e^8); rescale f_ = exp2(dm') == exp(dm);
// ssum/invl mathematically unchanged.
// Session-measured constraints baked in:
//  - V must use GLL16 DMA staging (V-in-VGPR x3: +21-25%).
//  - Stage distance 3 + end-of-period vmcnt(4) (distance-2: +9%).
//  - S-chain is the critical path; trimming its serial ops converts ~1:1
//    (max3 0.5, cvt_pk 2.5, permlane32 0.7, permlane16 1.3 us).
__global__ __launch_bounds__(768, 3) void attn_kernel(
        const ushort_t* __restrict__ QK, const ushort_t* __restrict__ V,
        const float* __restrict__ feat, const float* __restrict__ gamma,
        float* __restrict__ out) {
    __shared__ ushort_t Vl[3][16384];                // V tile [512d][32j] x3, swizzled
    __shared__ ushort_t Kl3[3][4096];                // K 2-tile bufs x3, XOR-swizzled
    __shared__ ushort_t Pl[2][4096];                 // P banks (2 tiles each)
    __shared__ float    fl[2][128];                  // per-q rescale, [bank][tt*64+q]
    __shared__ __align__(16) unsigned flagl[2][8];   // [bank][tt*4+qt]
    __shared__ float    invl[64];                    // final 1/ssum per q

    int bid = blockIdx.x;
    int lid = (bid & 7) * 32 + (bid >> 3);  // XCD-contiguous: one batch per 2 XCDs
    int b  = lid >> 6;
    int i0 = (lid & 63) * 64;

    int tid = threadIdx.x;
    int l = tid & 63, w = tid >> 6;
    int lr = l & 15, lg = l >> 4;
    int ds = (w >= 4) ? (w - 4) : 0;        // 0..7, 64-channel slice

    const ushort_t* QKb = QK + (size_t)b * N_ * NQK_;
    const ushort_t* Vb  = V  + (size_t)b * C_ * N_;

    // ---- S-wave persistent state
    bf16x8_t qf0 = {}, qf1 = {};
    const ushort_t* ksrc = nullptr;
    float mreg = -1e30f, ssum = 0.0f;       // ssum group-partial (reduced at end)
    const int maskk = (lr & 7) << 4;  // K read swizzle
    if (w < 4) {
        qf0 = load8(QKb + (size_t)(i0 + w * 16 + lr) * NQK_ + lg * 8);
        qf1 = load8(QKb + (size_t)(i0 + w * 16 + lr) * NQK_ + 32 + lg * 8);
        int p = w * 1024 + l * 16;
        int o = p ^ (((p >> 7) & 7) << 4);
        ksrc = QKb + (size_t)(o >> 7) * NQK_ + 64 + ((o & 127) >> 1);
    }

    // ---- PV-wave persistent state (round-8 V layout, verbatim)
    int cst = (l & 7) ^ (l >> 3);
    const ushort_t* vsrc = Vb + (size_t)(ds * 64 + 2 * (l >> 3) + (cst >> 2)) * N_
                              + (cst & 3) * 8;
    int c2 = ((lr & 1) * 4 + lg) ^ (lr >> 1);
    const int vread = ds * 2048 + (lr >> 1) * 64 + c2 * 8;   // ushorts; + dt*512
    f32x4_t acc[4][4] = {};

    // prologue: S stages K periods 0,1 (buf0,buf1), waits buf0 (buf1 in flight).
    // PV stages V(0),V(1),V(2) into bufs 0,1,2 (retired under vmcnt(4) cadence).
    if (w < 4) {
        GLL16(ksrc,                         &Kl3[0][w * 512]);
        GLL16(ksrc + (size_t)1 * 32 * NQK_, &Kl3[0][2048 + w * 512]);
        GLL16(ksrc + (size_t)2 * 32 * NQK_, &Kl3[1][w * 512]);
        GLL16(ksrc + (size_t)3 * 32 * NQK_, &Kl3[1][2048 + w * 512]);
        asm volatile("s_waitcnt vmcnt(2)" ::: "memory");
    } else {
        #pragma unroll
        for (int h = 0; h < 4; ++h)
            GLL16(vsrc + (size_t)h * 16 * N_,      &Vl[0][ds * 2048 + h * 512]);
        #pragma unroll
        for (int h = 0; h < 4; ++h)
            GLL16(vsrc + (size_t)h * 16 * N_ + 32, &Vl[1][ds * 2048 + h * 512]);
        #pragma unroll
        for (int h = 0; h < 4; ++h)
            GLL16(vsrc + (size_t)h * 16 * N_ + 64, &Vl[2][ds * 2048 + h * 512]);
    }
    asm volatile("" ::: "memory");
    __builtin_amdgcn_s_barrier();
    asm volatile("" ::: "memory");

// pack 2 f32 -> 1 u32 of 2 bf16 (RNE; src0 -> low 16) in one VALU op.
// Pure function: no volatile, no clobbers — compiler may schedule freely.
#define CVTPK(DST, LO, HI) \
    asm("v_cvt_pk_bf16_f32 %0, %1, %2" : "=v"(DST) : "v"(LO), "v"(HI))

#define SOFTMAX_WRITE(SO0, SO1, PM, TT)                                        \
    {                                                                          \
        float mA_ = fmaxf(fmaxf(SO0[0], SO0[1]), SO0[2]);   /* v_max3 */       \
        float mB_ = fmaxf(fmaxf(SO0[3], SO1[0]), SO1[1]);   /* v_max3 */       \
        float mC_ = fmaxf(SO1[2], SO1[3]);                                     \
        float pmax = fmaxf(fmaxf(mA_, mB_), mC_);           /* v_max3 */       \
        pmax = xmax16(pmax);                       /* VALU permlane16_swap */  \
        pmax = xmax32(pmax);                       /* VALU permlane32_swap */  \
        bool anyneed = __any(pmax > mreg + THR2_);                             \
        if (anyneed) {                                                         \
            float mn = fmaxf(mreg, pmax);                                      \
            float f_ = exp2f(mreg - mn);                                       \
            mreg = mn; ssum *= f_;                                             \
            if (lg == 0) fl[PM][(TT) * 64 + w * 16 + lr] = f_;                 \
        }                                                                      \
        if (l == 0) flagl[PM][(TT) * 4 + w] = anyneed ? 1u : 0u;               \
        float e00 = exp2f(SO0[0]-mreg), e01 = exp2f(SO0[1]-mreg);              \
        float e02 = exp2f(SO0[2]-mreg), e03 = exp2f(SO0[3]-mreg);              \
        float e10 = exp2f(SO1[0]-mreg), e11 = exp2f(SO1[1]-mreg);              \
        float e12 = exp2f(SO1[2]-mreg), e13 = exp2f(SO1[3]-mreg);              \
        ssum += (e00+e01)+(e02+e03)+(e10+e11)+(e12+e13);  /* group-partial */  \
        int lt = lr + (lg >> 1) * 16;                                          \
        uint2 w0v, w1v;                                                        \
        CVTPK(w0v.x, e00, e01); CVTPK(w0v.y, e02, e03);                        \
        CVTPK(w1v.x, e10, e11); CVTPK(w1v.y, e12, e13);                        \
        *reinterpret_cast<uint2*>(&Pl[PM][(TT)*2048 + w*512 + lt*8 + (lg&1)*4]) = w0v; \
        *reinterpret_cast<uint2*>(&Pl[PM][(TT)*2048 + w*512 + (lt+32)*8 + (lg&1)*4]) = w1v; \
    }

// PV: consume tile (P bank PB, slot TT, V buf VB); vf reads -> lgkm(0) ->
// stage tile STJ into the freed V buf (STJ%3==VB) -> rescale -> lazy-pa MFMA.
#define PVSTEP(PB, TT, VB, STJ, DOSTAGE)                                       \
    {                                                                          \
        bf16x8_t vf[4];                                                        \
        _Pragma("unroll") for (int dt = 0; dt < 4; ++dt)                       \
            vf[dt] = load8(&Vl[VB][vread + dt * 512]);                         \
        asm volatile("s_waitcnt lgkmcnt(0)" ::: "memory");                     \
        if (DOSTAGE) {                                                         \
            const ushort_t* vsT = vsrc + (STJ) * 32;                           \
            _Pragma("unroll") for (int h = 0; h < 4; ++h)                      \
                GLL16(vsT + (size_t)h * 16 * N_, &Vl[VB][ds * 2048 + h * 512]); \
        }                                                                      \
        uint4 fv = *reinterpret_cast<const uint4*>(&flagl[PB][(TT) * 4]);      \
        if ((int)__builtin_amdgcn_readfirstlane(fv.x)) {                       \
            float fq = fl[PB][(TT) * 64 + lr];                                 \
            _Pragma("unroll") for (int dt = 0; dt < 4; ++dt) acc[dt][0] *= fq; \
        }                                                                      \
        if ((int)__builtin_amdgcn_readfirstlane(fv.y)) {                       \
            float fq = fl[PB][(TT) * 64 + 16 + lr];                            \
            _Pragma("unroll") for (int dt = 0; dt < 4; ++dt) acc[dt][1] *= fq; \
        }                                                                      \
        if ((int)__builtin_amdgcn_readfirstlane(fv.z)) {                       \
            float fq = fl[PB][(TT) * 64 + 32 + lr];                            \
            _Pragma("unroll") for (int dt = 0; dt < 4; ++dt) acc[dt][2] *= fq; \
        }                                                                      \
        if ((int)__builtin_amdgcn_readfirstlane(fv.w)) {                       \
            float fq = fl[PB][(TT) * 64 + 48 + lr];                            \
            _Pragma("unroll") for (int dt = 0; dt < 4; ++dt) acc[dt][3] *= fq; \
        }                                                                      \
        __builtin_amdgcn_s_setprio(1);                                         \
        _Pragma("unroll") for (int qt = 0; qt < 4; ++qt) {                     \
            bf16x8_t pa = load8(&Pl[PB][(TT) * 2048 + qt * 512 + l * 8]);      \
            _Pragma("unroll") for (int dt = 0; dt < 4; ++dt)                   \
                acc[dt][qt] = __builtin_amdgcn_mfma_f32_16x16x32_bf16(         \
                    vf[dt], pa, acc[dt][qt], 0, 0, 0);                         \
        }                                                                      \
        __builtin_amdgcn_s_setprio(0);                                         \
    }

    for (int p = 0; p < NP_; ++p) {
        int pb = p % 3;
        if (w < 4) {
            // stage K for period p+2
            if (p + 2 < NP_) {
                int pn = pb + 2; if (pn >= 3) pn -= 3;
                GLL16(ksrc + (size_t)(2 * p + 4) * 32 * NQK_, &Kl3[pn][w * 512]);
                GLL16(ksrc + (size_t)(2 * p + 5) * 32 * NQK_, &Kl3[pn][2048 + w * 512]);
            }
            const ushort_t* kbp = &Kl3[pb][0];
            // tile 2p
            bf16x8_t kf00, kf01, kf10, kf11;
            { int o = (lr << 7) + (lg << 4);              kf00 = load8(kbp + ((o ^ maskk) >> 1)); }
            { int o = (lr << 7) + 64 + (lg << 4);         kf01 = load8(kbp + ((o ^ maskk) >> 1)); }
            { int o = ((16 + lr) << 7) + (lg << 4);       kf10 = load8(kbp + ((o ^ maskk) >> 1)); }
            { int o = ((16 + lr) << 7) + 64 + (lg << 4);  kf11 = load8(kbp + ((o ^ maskk) >> 1)); }
            f32x4_t s00 = {0.f,0.f,0.f,0.f}, s01 = {0.f,0.f,0.f,0.f};
            s00 = __builtin_amdgcn_mfma_f32_16x16x32_bf16(kf00, qf0, s00, 0,0,0);
            s00 = __builtin_amdgcn_mfma_f32_16x16x32_bf16(kf01, qf1, s00, 0,0,0);
            s01 = __builtin_amdgcn_mfma_f32_16x16x32_bf16(kf10, qf0, s01, 0,0,0);
            s01 = __builtin_amdgcn_mfma_f32_16x16x32_bf16(kf11, qf1, s01, 0,0,0);
            // tile 2p+1
            const ushort_t* kbq = kbp + 2048;
            bf16x8_t kg00, kg01, kg10, kg11;
            { int o = (lr << 7) + (lg << 4);              kg00 = load8(kbq + ((o ^ maskk) >> 1)); }
            { int o = (lr << 7) + 64 + (lg << 4);         kg01 = load8(kbq + ((o ^ maskk) >> 1)); }
            { int o = ((16 + lr) << 7) + (lg << 4);       kg10 = load8(kbq + ((o ^ maskk) >> 1)); }
            { int o = ((16 + lr) << 7) + 64 + (lg << 4);  kg11 = load8(kbq + ((o ^ maskk) >> 1)); }
            f32x4_t s10 = {0.f,0.f,0.f,0.f}, s11 = {0.f,0.f,0.f,0.f};
            s10 = __builtin_amdgcn_mfma_f32_16x16x32_bf16(kg00, qf0, s10, 0,0,0);
            s10 = __builtin_amdgcn_mfma_f32_16x16x32_bf16(kg01, qf1, s10, 0,0,0);
            s11 = __builtin_amdgcn_mfma_f32_16x16x32_bf16(kg10, qf0, s11, 0,0,0);
            s11 = __builtin_amdgcn_mfma_f32_16x16x32_bf16(kg11, qf1, s11, 0,0,0);
            // softmax 2p (while 2p+1's MFMAs retire), then 2p+1
            int bank = p & 1;
            SOFTMAX_WRITE(s00, s01, bank, 0)
            SOFTMAX_WRITE(s10, s11, bank, 1)
            asm volatile("s_waitcnt vmcnt(2) lgkmcnt(0)" ::: "memory");
        } else {
            if (p >= 1) {
                int pbk = (p - 1) & 1;
                int j0 = 2 * p - 2, j1 = 2 * p - 1;
                PVSTEP(pbk, 0, j0 % 3, j0 + 3, (j0 + 3 < NT_))
                PVSTEP(pbk, 1, j1 % 3, j1 + 3, (j1 + 3 < NT_))
            }
            // period 0: nothing to consume; prologue staged V(0..2).
            asm volatile("s_waitcnt vmcnt(4)" ::: "memory");
        }
        asm volatile("" ::: "memory");
        __builtin_amdgcn_s_barrier();
        asm volatile("" ::: "memory");
    }

    // tail A: S reduces group-partial ssum, publishes invl;
    //         PV drains the last V stage (tile 127).
    if (w < 4) {
        ssum += __shfl_xor(ssum, 16);
        ssum += __shfl_xor(ssum, 32);
        if (lg == 0) invl[w * 16 + lr] = 1.0f / ssum;
        asm volatile("s_waitcnt lgkmcnt(0)" ::: "memory");
    } else {
        asm volatile("s_waitcnt vmcnt(0)" ::: "memory");
    }
    asm volatile("" ::: "memory");
    __builtin_amdgcn_s_barrier();
    asm volatile("" ::: "memory");

    // tail B: PV consumes tiles 126 (buf 126%3=0), 127 (buf 127%3=1); bank 1.
    if (w >= 4) {
        PVSTEP(1, 0, 0, 0, false)
        PVSTEP(1, 1, 1, 0, false)
        asm volatile("s_waitcnt lgkmcnt(0)" ::: "memory");

        // epilogue: coalesced out = gamma*acc/l + feat (D[d][q])
        float g = gamma[0];
        float iq0 = invl[lr], iq1 = invl[16 + lr], iq2 = invl[32 + lr], iq3 = invl[48 + lr];
        #pragma unroll
        for (int dt = 0; dt < 4; ++dt) {
            #pragma unroll
            for (int r = 0; r < 4; ++r) {
                size_t row = ((size_t)b * C_ + ds * 64 + dt * 16 + lg * 4 + r) * N_;
                size_t i0r = row + i0;
                { size_t idx = i0r + lr;      out[idx] = g * acc[dt][0][r] * iq0 + feat[idx]; }
                { size_t idx = i0r + 16 + lr; out[idx] = g * acc[dt][1][r] * iq1 + feat[idx]; }
                { size_t idx = i0r + 32 + lr; out[idx] = g * acc[dt][2][r] * iq2 + feat[idx]; }
                { size_t idx = i0r + 48 + lr; out[idx] = g * acc[dt][3][r] * iq3 + feat[idx]; }
            }
        }
    }
#undef PVSTEP
#undef SOFTMAX_WRITE
#undef CVTPK
}

// ---------------------------------------------------------------- launch
extern "C" void kernel_launch(void* const* d_in, const int* in_sizes, int n_in,
                              void* d_out, int out_size, void* d_ws, size_t ws_size,
                              hipStream_t stream) {
    const float* feat  = (const float*)d_in[0];
    const float* w1    = (const float*)d_in[1];
    const float* b1    = (const float*)d_in[2];
    const float* w2    = (const float*)d_in[3];
    const float* b2    = (const float*)d_in[4];
    const float* w3    = (const float*)d_in[5];
    const float* b3    = (const float*)d_in[6];
    const float* gamma = (const float*)d_in[7];
    float* out = (float*)d_out;

    char* ws = (char*)d_ws;
    ushort_t* Xt      = (ushort_t*)(ws);
    ushort_t* Wb      = (ushort_t*)(ws + 16777216);
    float*    biasAll = (float*)   (ws + 17432576);
    ushort_t* QKp     = (ushort_t*)(ws + 17435136);
    ushort_t* Vp      = (ushort_t*)(ws + 21629440);
    if (ws_size < 38406656) return;

    hipLaunchKernelGGL(transpose_cast_x, dim3(64, 8, 5), dim3(256), 0, stream,
                       feat, Xt, w1, b1, w2, b2, w3, b3, Wb, biasAll);
    hipLaunchKernelGGL(gemm_qkv_kernel, dim3(1280), dim3(256), 0, stream,
                       Xt, Wb, biasAll, QKp, Vp);
    hipLaunchKernelGGL(attn_kernel, dim3(256), dim3(768), 0, stream,
                       QKp, Vp, feat, gamma, out);
}

// Round 16
// 136.573 us; speedup vs baseline: 1.0194x; 1.0194x over previous
//
#include <hip/hip_runtime.h>
#include <hip/hip_bf16.h>

typedef __attribute__((ext_vector_type(8))) short bf16x8_t;
typedef __attribute__((ext_vector_type(4))) float f32x4_t;

#define B_   4
#define C_   512
#define N_   4096
#define NQK_ 128   // Q(64) | K(64) channel-concat width
#define NT_  128   // N_/32 j-tiles
#define NP_  64    // 2-tile barrier periods
#define LOG2E_ 1.44269504088896340736f
#define THR2_  11.5415603f   // 8 * log2e — defer-max threshold in log2 domain

typedef unsigned short ushort_t;

__device__ __forceinline__ ushort_t f2bf(float f) {
    union { float f; unsigned int u; } un; un.f = f;
    unsigned int r = un.u + 0x7FFF + ((un.u >> 16) & 1); // RNE
    return (ushort_t)(r >> 16);
}

__device__ __forceinline__ bf16x8_t load8(const ushort_t* p) {
    return *reinterpret_cast<const bf16x8_t*>(p);
}

// bare v_exp_f32: computes 2^x in ONE VALU op. Round 15 used exp2f(), which
// maps to the precise ocml exp2 (several ops: VALUBusy 33.9->39.2, +1.7us).
// The builtin is the fast path __expf used before, minus its v_mul.
__device__ __forceinline__ float exp2fast(float x) {
    return __builtin_amdgcn_exp2f(x);
}

// lane[i] <-> lane[i^32] max via v_permlane32_swap_b32 (VALU pipe) replacing
// the ds-pipe __shfl_xor hop. Value-semantics builtin (round 10's raw-asm
// self-swap aliasing trap does not apply). max(r0,r1) is correct under
// EITHER swap orientation: each output lane holds self or partner.
__device__ __forceinline__ float xmax32(float x) {
    unsigned u = __float_as_uint(x);
    auto r = __builtin_amdgcn_permlane32_swap(u, u, false, false);
    return fmaxf(__uint_as_float(r[0]), __uint_as_float(r[1]));
}

// lane[i] <-> lane[i^16] max via v_permlane16_swap_b32 — same argument.
// With both, the whole pmax reduce is VALU-only (zero lgkm round-trips).
__device__ __forceinline__ float xmax16(float x) {
    unsigned u = __float_as_uint(x);
    auto r = __builtin_amdgcn_permlane16_swap(u, u, false, false);
    return fmaxf(__uint_as_float(r[0]), __uint_as_float(r[1]));
}

// async global->LDS, 16B per lane; dest is wave-uniform base (+ lane*16 in HW)
#define GLL16(g, l) __builtin_amdgcn_global_load_lds( \
    (const __attribute__((address_space(1))) unsigned int*)(g), \
    (__attribute__((address_space(3))) unsigned int*)(l), 16, 0, 0)

// ------------------------------------------- transpose+cast x -> Xt[b][n][c]
// z==4: weight/bias cast (folded-in former cast_w kernel)
__global__ __launch_bounds__(256) void transpose_cast_x(
        const float* __restrict__ x, ushort_t* __restrict__ Xt,
        const float* __restrict__ w1, const float* __restrict__ b1,
        const float* __restrict__ w2, const float* __restrict__ b2,
        const float* __restrict__ w3, const float* __restrict__ b3,
        ushort_t* __restrict__ Wb, float* __restrict__ bias_all) {
    if (blockIdx.z == 4) {
        int bid = blockIdx.y * 64 + blockIdx.x;          // 0..511
        int t0 = bid * 256 + threadIdx.x;                // 0..131071
        for (int idx = t0; idx < 640 * 512 + 640; idx += 131072) {
            if (idx < 64 * 512) {
                Wb[idx] = f2bf(w1[idx]);
            } else if (idx < 128 * 512) {
                Wb[idx] = f2bf(w2[idx - 64 * 512]);
            } else if (idx < 640 * 512) {
                Wb[idx] = f2bf(w3[idx - 128 * 512]);
            } else {
                int i = idx - 640 * 512;
                bias_all[i] = (i < 64) ? b1[i] : (i < 128 ? b2[i - 64] : b3[i - 128]);
            }
        }
        return;
    }
    int b = blockIdx.z, c0 = blockIdx.y * 64, n0 = blockIdx.x * 64;
    int tid = threadIdx.x;
    __shared__ float t[64][65];
    const float* xb = x + ((size_t)b * C_ + c0) * N_ + n0;
    #pragma unroll
    for (int it = 0; it < 4; ++it) {
        int cl = it * 16 + (tid >> 4), nq = (tid & 15) * 4;
        const float4 v = *reinterpret_cast<const float4*>(xb + (size_t)cl * N_ + nq);
        t[cl][nq + 0] = v.x; t[cl][nq + 1] = v.y;
        t[cl][nq + 2] = v.z; t[cl][nq + 3] = v.w;
    }
    __syncthreads();
    #pragma unroll
    for (int it = 0; it < 4; ++it) {
        int nl = it * 16 + (tid >> 4), cq = (tid & 15) * 4;
        ushort4 o;
        o.x = f2bf(t[cq + 0][nl]); o.y = f2bf(t[cq + 1][nl]);
        o.z = f2bf(t[cq + 2][nl]); o.w = f2bf(t[cq + 3][nl]);
        *reinterpret_cast<ushort4*>(&Xt[((size_t)b * N_ + n0 + nl) * C_ + c0 + cq]) = o;
    }
}

// ---------------------------------------------------- fused QK + V GEMMs
// Uniform 64x128 output tiles, 1280 equal blocks (exactly 5/CU). 24KB LDS ->
// 2 blocks/CU co-resident. m97 staging recipe, vmcnt(3) cadence.
// Q columns (wc==0, cols 0-63) scaled by log2e at the epilogue: QK^T lands
// in the log2 domain so attn's softmax uses bare v_exp_f32.
__global__ __launch_bounds__(256) void gemm_qkv_kernel(
        const ushort_t* __restrict__ Xt, const ushort_t* __restrict__ Wb,
        const float* __restrict__ bias, ushort_t* __restrict__ QK,
        ushort_t* __restrict__ V) {
    __shared__ ushort_t Al[2][2048];   // 64 rows x 32 k, linear
    __shared__ ushort_t Bl[2][4096];   // 128 rows x 32 k, linear
    int bid = blockIdx.x;
    int tid = threadIdx.x;
    int l = tid & 63, w = tid >> 6;
    int wr = w >> 1, wc = w & 1;       // 2 row-strips(32) x 2 col-strips(64)
    int lr = l & 15, lg = l >> 4;

    int b, n0, d0 = 0;
    bool isQK = (bid < 256);
    const ushort_t* asrc;
    const ushort_t* bsrc;
    if (isQK) {
        b = bid >> 6; n0 = (bid & 63) * 64;
        asrc = Xt + ((size_t)b * N_ + n0) * 512;   // A rows = 64 n-rows
        bsrc = Wb;                                  // B rows = 128 qk cols
    } else {
        int v = bid - 256;
        b = v >> 8; d0 = ((v >> 5) & 7) * 64; n0 = (v & 31) * 128;
        asrc = Wb + (size_t)(128 + d0) * 512;       // A rows = 64 d-rows of Wv
        bsrc = Xt + ((size_t)b * N_ + n0) * 512;    // B rows = 128 n-rows
    }
    const ushort_t* ast = asrc + (size_t)(l >> 2) * 512 + (l & 3) * 8;
    const ushort_t* bst = bsrc + (size_t)(l >> 2) * 512 + (l & 3) * 8;

#define STAGEK(BUF, K0)                                                          \
    {                                                                            \
        GLL16(ast + (size_t)(w * 16) * 512 + (K0),      &Al[BUF][w * 512]);      \
        GLL16(bst + (size_t)(w * 32) * 512 + (K0),      &Bl[BUF][w * 1024]);     \
        GLL16(bst + (size_t)(w * 32 + 16) * 512 + (K0), &Bl[BUF][w * 1024 + 512]); \
    }

    f32x4_t acc[2][4] = {};
    STAGEK(0, 0)
    for (int i = 0; i < 16; ++i) {
        int cur = i & 1;
        if (i < 15) {
            STAGEK(cur ^ 1, (i + 1) * 32)
            asm volatile("s_waitcnt vmcnt(3)" ::: "memory");  // cur's 3 landed
        } else {
            asm volatile("s_waitcnt vmcnt(0)" ::: "memory");
        }
        asm volatile("" ::: "memory");
        __builtin_amdgcn_s_barrier();
        asm volatile("" ::: "memory");
        bf16x8_t a[2], b8[4];
        #pragma unroll
        for (int f = 0; f < 2; ++f)
            a[f]  = load8(&Al[cur][(wr * 32 + f * 16 + lr) * 32 + lg * 8]);
        #pragma unroll
        for (int f = 0; f < 4; ++f)
            b8[f] = load8(&Bl[cur][(wc * 64 + f * 16 + lr) * 32 + lg * 8]);
        #pragma unroll
        for (int fi = 0; fi < 2; ++fi)
            #pragma unroll
            for (int fj = 0; fj < 4; ++fj)
                acc[fi][fj] = __builtin_amdgcn_mfma_f32_16x16x32_bf16(
                    a[fi], b8[fj], acc[fi][fj], 0, 0, 0);
        asm volatile("" ::: "memory");
        __builtin_amdgcn_s_barrier();   // all reads of cur done before restage
        asm volatile("" ::: "memory");
    }
#undef STAGEK

    if (isQK) {
        // wc==0 covers Q columns (0-63): fold log2e into Q so QK^T lands in
        // the log2 domain (wave-uniform branch).
        float sc = (wc == 0) ? LOG2E_ : 1.0f;
        #pragma unroll
        for (int fi = 0; fi < 2; ++fi)
            #pragma unroll
            for (int fj = 0; fj < 4; ++fj)
                #pragma unroll
                for (int r = 0; r < 4; ++r) {
                    int n = n0 + wr * 32 + fi * 16 + lg * 4 + r;
                    int col = wc * 64 + fj * 16 + lr;
                    QK[((size_t)b * N_ + n) * NQK_ + col] =
                        f2bf((acc[fi][fj][r] + bias[col]) * sc);
                }
    } else {
        #pragma unroll
        for (int fi = 0; fi < 2; ++fi)
            #pragma unroll
            for (int fj = 0; fj < 4; ++fj)
                #pragma unroll
                for (int r = 0; r < 4; ++r) {
                    int d = d0 + wr * 32 + fi * 16 + lg * 4 + r;
                    int n = n0 + wc * 64 + fj * 16 + lr;
                    V[((size_t)b * C_ + d) * N_ + n] = f2bf(acc[fi][fj][r] + bias[128 + d]);
                }
    }
}

// ---------------------------------------------------- fused flash attention
// grid 256 x 768thr (12 waves). Round 32 = round 15 with the exp symbol
// fixed: exp2f() (precise ocml exp2, ~5 VALU ops — VALUBusy 33.9->39.2,
// +1.7us) -> __builtin_amdgcn_exp2f (ONE v_exp_f32). The log2-domain math
// itself was verified by round 15's pass (absmax 0.03125). vs round 14 the
// exp block is now 9 single-instruction v_exp vs 9 mul + 9 exp.
// Session-measured constraints baked in:
//  - V must use GLL16 DMA staging (V-in-VGPR x3: +21-25%).
//  - Stage distance 3 + end-of-period vmcnt(4) (distance-2: +9%).
//  - S-chain is the critical path; trimming its serial ops converts ~1:1
//    (max3 0.5, cvt_pk 2.5, permlane32 0.7, permlane16 1.3 us).
__global__ __launch_bounds__(768, 3) void attn_kernel(
        const ushort_t* __restrict__ QK, const ushort_t* __restrict__ V,
        const float* __restrict__ feat, const float* __restrict__ gamma,
        float* __restrict__ out) {
    __shared__ ushort_t Vl[3][16384];                // V tile [512d][32j] x3, swizzled
    __shared__ ushort_t Kl3[3][4096];                // K 2-tile bufs x3, XOR-swizzled
    __shared__ ushort_t Pl[2][4096];                 // P banks (2 tiles each)
    __shared__ float    fl[2][128];                  // per-q rescale, [bank][tt*64+q]
    __shared__ __align__(16) unsigned flagl[2][8];   // [bank][tt*4+qt]
    __shared__ float    invl[64];                    // final 1/ssum per q

    int bid = blockIdx.x;
    int lid = (bid & 7) * 32 + (bid >> 3);  // XCD-contiguous: one batch per 2 XCDs
    int b  = lid >> 6;
    int i0 = (lid & 63) * 64;

    int tid = threadIdx.x;
    int l = tid & 63, w = tid >> 6;
    int lr = l & 15, lg = l >> 4;
    int ds = (w >= 4) ? (w - 4) : 0;        // 0..7, 64-channel slice

    const ushort_t* QKb = QK + (size_t)b * N_ * NQK_;
    const ushort_t* Vb  = V  + (size_t)b * C_ * N_;

    // ---- S-wave persistent state
    bf16x8_t qf0 = {}, qf1 = {};
    const ushort_t* ksrc = nullptr;
    float mreg = -1e30f, ssum = 0.0f;       // ssum group-partial (reduced at end)
    const int maskk = (lr & 7) << 4;  // K read swizzle
    if (w < 4) {
        qf0 = load8(QKb + (size_t)(i0 + w * 16 + lr) * NQK_ + lg * 8);
        qf1 = load8(QKb + (size_t)(i0 + w * 16 + lr) * NQK_ + 32 + lg * 8);
        int p = w * 1024 + l * 16;
        int o = p ^ (((p >> 7) & 7) << 4);
        ksrc = QKb + (size_t)(o >> 7) * NQK_ + 64 + ((o & 127) >> 1);
    }

    // ---- PV-wave persistent state (round-8 V layout, verbatim)
    int cst = (l & 7) ^ (l >> 3);
    const ushort_t* vsrc = Vb + (size_t)(ds * 64 + 2 * (l >> 3) + (cst >> 2)) * N_
                              + (cst & 3) * 8;
    int c2 = ((lr & 1) * 4 + lg) ^ (lr >> 1);
    const int vread = ds * 2048 + (lr >> 1) * 64 + c2 * 8;   // ushorts; + dt*512
    f32x4_t acc[4][4] = {};

    // prologue: S stages K periods 0,1 (buf0,buf1), waits buf0 (buf1 in flight).
    // PV stages V(0),V(1),V(2) into bufs 0,1,2 (retired under vmcnt(4) cadence).
    if (w < 4) {
        GLL16(ksrc,                         &Kl3[0][w * 512]);
        GLL16(ksrc + (size_t)1 * 32 * NQK_, &Kl3[0][2048 + w * 512]);
        GLL16(ksrc + (size_t)2 * 32 * NQK_, &Kl3[1][w * 512]);
        GLL16(ksrc + (size_t)3 * 32 * NQK_, &Kl3[1][2048 + w * 512]);
        asm volatile("s_waitcnt vmcnt(2)" ::: "memory");
    } else {
        #pragma unroll
        for (int h = 0; h < 4; ++h)
            GLL16(vsrc + (size_t)h * 16 * N_,      &Vl[0][ds * 2048 + h * 512]);
        #pragma unroll
        for (int h = 0; h < 4; ++h)
            GLL16(vsrc + (size_t)h * 16 * N_ + 32, &Vl[1][ds * 2048 + h * 512]);
        #pragma unroll
        for (int h = 0; h < 4; ++h)
            GLL16(vsrc + (size_t)h * 16 * N_ + 64, &Vl[2][ds * 2048 + h * 512]);
    }
    asm volatile("" ::: "memory");
    __builtin_amdgcn_s_barrier();
    asm volatile("" ::: "memory");

// pack 2 f32 -> 1 u32 of 2 bf16 (RNE; src0 -> low 16) in one VALU op.
// Pure function: no volatile, no clobbers — compiler may schedule freely.
#define CVTPK(DST, LO, HI) \
    asm("v_cvt_pk_bf16_f32 %0, %1, %2" : "=v"(DST) : "v"(LO), "v"(HI))

#define SOFTMAX_WRITE(SO0, SO1, PM, TT)                                        \
    {                                                                          \
        float mA_ = fmaxf(fmaxf(SO0[0], SO0[1]), SO0[2]);   /* v_max3 */       \
        float mB_ = fmaxf(fmaxf(SO0[3], SO1[0]), SO1[1]);   /* v_max3 */       \
        float mC_ = fmaxf(SO1[2], SO1[3]);                                     \
        float pmax = fmaxf(fmaxf(mA_, mB_), mC_);           /* v_max3 */       \
        pmax = xmax16(pmax);                       /* VALU permlane16_swap */  \
        pmax = xmax32(pmax);                       /* VALU permlane32_swap */  \
        bool anyneed = __any(pmax > mreg + THR2_);                             \
        if (anyneed) {                                                         \
            float mn = fmaxf(mreg, pmax);                                      \
            float f_ = exp2fast(mreg - mn);                                    \
            mreg = mn; ssum *= f_;                                             \
            if (lg == 0) fl[PM][(TT) * 64 + w * 16 + lr] = f_;                 \
        }                                                                      \
        if (l == 0) flagl[PM][(TT) * 4 + w] = anyneed ? 1u : 0u;               \
        float e00 = exp2fast(SO0[0]-mreg), e01 = exp2fast(SO0[1]-mreg);        \
        float e02 = exp2fast(SO0[2]-mreg), e03 = exp2fast(SO0[3]-mreg);        \
        float e10 = exp2fast(SO1[0]-mreg), e11 = exp2fast(SO1[1]-mreg);        \
        float e12 = exp2fast(SO1[2]-mreg), e13 = exp2fast(SO1[3]-mreg);        \
        ssum += (e00+e01)+(e02+e03)+(e10+e11)+(e12+e13);  /* group-partial */  \
        int lt = lr + (lg >> 1) * 16;                                          \
        uint2 w0v, w1v;                                                        \
        CVTPK(w0v.x, e00, e01); CVTPK(w0v.y, e02, e03);                        \
        CVTPK(w1v.x, e10, e11); CVTPK(w1v.y, e12, e13);                        \
        *reinterpret_cast<uint2*>(&Pl[PM][(TT)*2048 + w*512 + lt*8 + (lg&1)*4]) = w0v; \
        *reinterpret_cast<uint2*>(&Pl[PM][(TT)*2048 + w*512 + (lt+32)*8 + (lg&1)*4]) = w1v; \
    }

// PV: consume tile (P bank PB, slot TT, V buf VB); vf reads -> lgkm(0) ->
// stage tile STJ into the freed V buf (STJ%3==VB) -> rescale -> lazy-pa MFMA.
#define PVSTEP(PB, TT, VB, STJ, DOSTAGE)                                       \
    {                                                                          \
        bf16x8_t vf[4];                                                        \
        _Pragma("unroll") for (int dt = 0; dt < 4; ++dt)                       \
            vf[dt] = load8(&Vl[VB][vread + dt * 512]);                         \
        asm volatile("s_waitcnt lgkmcnt(0)" ::: "memory");                     \
        if (DOSTAGE) {                                                         \
            const ushort_t* vsT = vsrc + (STJ) * 32;                           \
            _Pragma("unroll") for (int h = 0; h < 4; ++h)                      \
                GLL16(vsT + (size_t)h * 16 * N_, &Vl[VB][ds * 2048 + h * 512]); \
        }                                                                      \
        uint4 fv = *reinterpret_cast<const uint4*>(&flagl[PB][(TT) * 4]);      \
        if ((int)__builtin_amdgcn_readfirstlane(fv.x)) {                       \
            float fq = fl[PB][(TT) * 64 + lr];                                 \
            _Pragma("unroll") for (int dt = 0; dt < 4; ++dt) acc[dt][0] *= fq; \
        }                                                                      \
        if ((int)__builtin_amdgcn_readfirstlane(fv.y)) {                       \
            float fq = fl[PB][(TT) * 64 + 16 + lr];                            \
            _Pragma("unroll") for (int dt = 0; dt < 4; ++dt) acc[dt][1] *= fq; \
        }                                                                      \
        if ((int)__builtin_amdgcn_readfirstlane(fv.z)) {                       \
            float fq = fl[PB][(TT) * 64 + 32 + lr];                            \
            _Pragma("unroll") for (int dt = 0; dt < 4; ++dt) acc[dt][2] *= fq; \
        }                                                                      \
        if ((int)__builtin_amdgcn_readfirstlane(fv.w)) {                       \
            float fq = fl[PB][(TT) * 64 + 48 + lr];                            \
            _Pragma("unroll") for (int dt = 0; dt < 4; ++dt) acc[dt][3] *= fq; \
        }                                                                      \
        __builtin_amdgcn_s_setprio(1);                                         \
        _Pragma("unroll") for (int qt = 0; qt < 4; ++qt) {                     \
            bf16x8_t pa = load8(&Pl[PB][(TT) * 2048 + qt * 512 + l * 8]);      \
            _Pragma("unroll") for (int dt = 0; dt < 4; ++dt)                   \
                acc[dt][qt] = __builtin_amdgcn_mfma_f32_16x16x32_bf16(         \
                    vf[dt], pa, acc[dt][qt], 0, 0, 0);                         \
        }                                                                      \
        __builtin_amdgcn_s_setprio(0);                                         \
    }

    for (int p = 0; p < NP_; ++p) {
        int pb = p % 3;
        if (w < 4) {
            // stage K for period p+2
            if (p + 2 < NP_) {
                int pn = pb + 2; if (pn >= 3) pn -= 3;
                GLL16(ksrc + (size_t)(2 * p + 4) * 32 * NQK_, &Kl3[pn][w * 512]);
                GLL16(ksrc + (size_t)(2 * p + 5) * 32 * NQK_, &Kl3[pn][2048 + w * 512]);
            }
            const ushort_t* kbp = &Kl3[pb][0];
            // tile 2p
            bf16x8_t kf00, kf01, kf10, kf11;
            { int o = (lr << 7) + (lg << 4);              kf00 = load8(kbp + ((o ^ maskk) >> 1)); }
            { int o = (lr << 7) + 64 + (lg << 4);         kf01 = load8(kbp + ((o ^ maskk) >> 1)); }
            { int o = ((16 + lr) << 7) + (lg << 4);       kf10 = load8(kbp + ((o ^ maskk) >> 1)); }
            { int o = ((16 + lr) << 7) + 64 + (lg << 4);  kf11 = load8(kbp + ((o ^ maskk) >> 1)); }
            f32x4_t s00 = {0.f,0.f,0.f,0.f}, s01 = {0.f,0.f,0.f,0.f};
            s00 = __builtin_amdgcn_mfma_f32_16x16x32_bf16(kf00, qf0, s00, 0,0,0);
            s00 = __builtin_amdgcn_mfma_f32_16x16x32_bf16(kf01, qf1, s00, 0,0,0);
            s01 = __builtin_amdgcn_mfma_f32_16x16x32_bf16(kf10, qf0, s01, 0,0,0);
            s01 = __builtin_amdgcn_mfma_f32_16x16x32_bf16(kf11, qf1, s01, 0,0,0);
            // tile 2p+1
            const ushort_t* kbq = kbp + 2048;
            bf16x8_t kg00, kg01, kg10, kg11;
            { int o = (lr << 7) + (lg << 4);              kg00 = load8(kbq + ((o ^ maskk) >> 1)); }
            { int o = (lr << 7) + 64 + (lg << 4);         kg01 = load8(kbq + ((o ^ maskk) >> 1)); }
            { int o = ((16 + lr) << 7) + (lg << 4);       kg10 = load8(kbq + ((o ^ maskk) >> 1)); }
            { int o = ((16 + lr) << 7) + 64 + (lg << 4);  kg11 = load8(kbq + ((o ^ maskk) >> 1)); }
            f32x4_t s10 = {0.f,0.f,0.f,0.f}, s11 = {0.f,0.f,0.f,0.f};
            s10 = __builtin_amdgcn_mfma_f32_16x16x32_bf16(kg00, qf0, s10, 0,0,0);
            s10 = __builtin_amdgcn_mfma_f32_16x16x32_bf16(kg01, qf1, s10, 0,0,0);
            s11 = __builtin_amdgcn_mfma_f32_16x16x32_bf16(kg10, qf0, s11, 0,0,0);
            s11 = __builtin_amdgcn_mfma_f32_16x16x32_bf16(kg11, qf1, s11, 0,0,0);
            // softmax 2p (while 2p+1's MFMAs retire), then 2p+1
            int bank = p & 1;
            SOFTMAX_WRITE(s00, s01, bank, 0)
            SOFTMAX_WRITE(s10, s11, bank, 1)
            asm volatile("s_waitcnt vmcnt(2) lgkmcnt(0)" ::: "memory");
        } else {
            if (p >= 1) {
                int pbk = (p - 1) & 1;
                int j0 = 2 * p - 2, j1 = 2 * p - 1;
                PVSTEP(pbk, 0, j0 % 3, j0 + 3, (j0 + 3 < NT_))
                PVSTEP(pbk, 1, j1 % 3, j1 + 3, (j1 + 3 < NT_))
            }
            // period 0: nothing to consume; prologue staged V(0..2).
            asm volatile("s_waitcnt vmcnt(4)" ::: "memory");
        }
        asm volatile("" ::: "memory");
        __builtin_amdgcn_s_barrier();
        asm volatile("" ::: "memory");
    }

    // tail A: S reduces group-partial ssum, publishes invl;
    //         PV drains the last V stage (tile 127).
    if (w < 4) {
        ssum += __shfl_xor(ssum, 16);
        ssum += __shfl_xor(ssum, 32);
        if (lg == 0) invl[w * 16 + lr] = 1.0f / ssum;
        asm volatile("s_waitcnt lgkmcnt(0)" ::: "memory");
    } else {
        asm volatile("s_waitcnt vmcnt(0)" ::: "memory");
    }
    asm volatile("" ::: "memory");
    __builtin_amdgcn_s_barrier();
    asm volatile("" ::: "memory");

    // tail B: PV consumes tiles 126 (buf 126%3=0), 127 (buf 127%3=1); bank 1.
    if (w >= 4) {
        PVSTEP(1, 0, 0, 0, false)
        PVSTEP(1, 1, 1, 0, false)
        asm volatile("s_waitcnt lgkmcnt(0)" ::: "memory");

        // epilogue: coalesced out = gamma*acc/l + feat (D[d][q])
        float g = gamma[0];
        float iq0 = invl[lr], iq1 = invl[16 + lr], iq2 = invl[32 + lr], iq3 = invl[48 + lr];
        #pragma unroll
        for (int dt = 0; dt < 4; ++dt) {
            #pragma unroll
            for (int r = 0; r < 4; ++r) {
                size_t row = ((size_t)b * C_ + ds * 64 + dt * 16 + lg * 4 + r) * N_;
                size_t i0r = row + i0;
                { size_t idx = i0r + lr;      out[idx] = g * acc[dt][0][r] * iq0 + feat[idx]; }
                { size_t idx = i0r + 16 + lr; out[idx] = g * acc[dt][1][r] * iq1 + feat[idx]; }
                { size_t idx = i0r + 32 + lr; out[idx] = g * acc[dt][2][r] * iq2 + feat[idx]; }
                { size_t idx = i0r + 48 + lr; out[idx] = g * acc[dt][3][r] * iq3 + feat[idx]; }
            }
        }
    }
#undef PVSTEP
#undef SOFTMAX_WRITE
#undef CVTPK
}

// ---------------------------------------------------------------- launch
extern "C" void kernel_launch(void* const* d_in, const int* in_sizes, int n_in,
                              void* d_out, int out_size, void* d_ws, size_t ws_size,
                              hipStream_t stream) {
    const float* feat  = (const float*)d_in[0];
    const float* w1    = (const float*)d_in[1];
    const float* b1    = (const float*)d_in[2];
    const float* w2    = (const float*)d_in[3];
    const float* b2    = (const float*)d_in[4];
    const float* w3    = (const float*)d_in[5];
    const float* b3    = (const float*)d_in[6];
    const float* gamma = (const float*)d_in[7];
    float* out = (float*)d_out;

    char* ws = (char*)d_ws;
    ushort_t* Xt      = (ushort_t*)(ws);
    ushort_t* Wb      = (ushort_t*)(ws + 16777216);
    float*    biasAll = (float*)   (ws + 17432576);
    ushort_t* QKp     = (ushort_t*)(ws + 17435136);
    ushort_t* Vp      = (ushort_t*)(ws + 21629440);
    if (ws_size < 38406656) return;

    hipLaunchKernelGGL(transpose_cast_x, dim3(64, 8, 5), dim3(256), 0, stream,
                       feat, Xt, w1, b1, w2, b2, w3, b3, Wb, biasAll);
    hipLaunchKernelGGL(gemm_qkv_kernel, dim3(1280), dim3(256), 0, stream,
                       Xt, Wb, biasAll, QKp, Vp);
    hipLaunchKernelGGL(attn_kernel, dim3(256), dim3(768), 0, stream,
                       QKp, Vp, feat, gamma, out);
}